// Round 4
// baseline (183.978 us; speedup 1.0000x reference)
//
#include <hip/hip_runtime.h>
#include <hip/hip_bf16.h>
#include <stdint.h>

#define NB    2048
#define NSENT 20
#define SEC   40
#define DD    100
#define UU    50
#define SP1   801
#define FBE   4832   // floats per tile buffer: 4000 data + 832 zeroed slop (pad reads)

typedef __attribute__((ext_vector_type(8))) short bf16x8;
typedef __attribute__((ext_vector_type(4))) float f32x4;

__device__ __forceinline__ unsigned f2bf(float f) {
  unsigned u = __float_as_uint(f);
  unsigned r = u + 0x7fffu + ((u >> 16) & 1u);   // RNE
  return r >> 16;
}

// two float4 (8 consecutive f32) -> bf16x8 via packed convert
__device__ __forceinline__ bf16x8 cvt8(f32x4 a, f32x4 b) {
  union { unsigned u[4]; bf16x8 v; } r;
  asm("v_cvt_pk_bf16_f32 %0, %1, %2" : "=v"(r.u[0]) : "v"(a[0]), "v"(a[1]));
  asm("v_cvt_pk_bf16_f32 %0, %1, %2" : "=v"(r.u[1]) : "v"(a[2]), "v"(a[3]));
  asm("v_cvt_pk_bf16_f32 %0, %1, %2" : "=v"(r.u[2]) : "v"(b[0]), "v"(b[1]));
  asm("v_cvt_pk_bf16_f32 %0, %1, %2" : "=v"(r.u[3]) : "v"(b[2]), "v"(b[3]));
  return r.v;
}

// async HBM -> LDS, 16B per lane, wave-uniform LDS base
#define GL16(gp, lp) __builtin_amdgcn_global_load_lds( \
    (const __attribute__((address_space(1))) unsigned*)(const void*)(gp), \
    (__attribute__((address_space(3))) unsigned*)(void*)(lp), 16, 0, 0)

// One 4-wave block per document. f32 h tile staged async into LDS (double-buffered);
// wave w owns u-tile w of C[u][s] = wh . h^T; bf16 conversion fused into frag reads.
__global__ __launch_bounds__(256, 4) void doc_kernel(
    const float* __restrict__ inputs, const float* __restrict__ vw,
    const float* __restrict__ wh, const float* __restrict__ wu,
    const float* __restrict__ bw, float* __restrict__ out) {
  __shared__ __align__(16) float fbuf[2][FBE];     // 2 x 19328 B
  __shared__ __align__(16) float epart[3 * 16 * 4];
  __shared__ float alphas[SEC];

  const int tid  = threadIdx.x;
  const int w    = tid >> 6, lane = tid & 63;
  const int col  = lane & 15, grp = lane >> 4;
  const int b    = blockIdx.x;

  const float* base = inputs + (size_t)b * SP1 * DD;

  // ---- issue tile-0 async loads immediately (wave w -> chunks 4w..4w+3) ----
  #pragma unroll
  for (int c = 0; c < 4; ++c) {
    int chunk = 4 * w + c;
    int g = chunk * 64 + lane;                  // 16B granule index
    if (g < 1000) GL16(base + g * 4, &fbuf[0][chunk * 256]);
  }

  // ---- zero the pad slop [4000, FBE) of both buffers (never overwritten) ----
  for (int i = tid; i < 2 * (FBE - 4000); i += 256) {
    int bb = i >= (FBE - 4000);
    fbuf[bb][4000 + (i - bb * (FBE - 4000))] = 0.f;
  }

  // ---- A fragments: this wave's 16 wh rows (u = 16w + col), resident ----
  bf16x8 afrag[4];
  {
    int u = w * 16 + col;
    #pragma unroll
    for (int kt = 0; kt < 4; ++kt) {
      bf16x8 f;
      #pragma unroll
      for (int j = 0; j < 8; ++j) {
        int k = kt * 32 + grp * 8 + j;
        float v = (u < UU && k < DD) ? wh[u * DD + k] : 0.f;
        f[j] = (short)f2bf(v);
      }
      afrag[kt] = f;
    }
  }

  // ---- wub[u=lane] = uvec[b]·wu[u] + bw[u] ----
  float wubacc;
  {
    int ur = lane < UU ? lane : UU - 1;
    const float4* uv4 = (const float4*)(inputs + ((size_t)b * SP1 + SP1 - 1) * DD);
    const float4* wr4 = (const float4*)(wu + ur * DD);
    float a0 = bw[ur];
    #pragma unroll 5
    for (int q = 0; q < 25; ++q) {
      float4 uq = uv4[q], wq = wr4[q];
      a0 = fmaf(uq.x, wq.x, a0); a0 = fmaf(uq.y, wq.y, a0);
      a0 = fmaf(uq.z, wq.z, a0); a0 = fmaf(uq.w, wq.w, a0);
    }
    wubacc = a0;
  }
  float vwr[4], wubr[4];
  #pragma unroll
  for (int r = 0; r < 4; ++r) {
    int u = w * 16 + grp * 4 + r;
    float wv = __shfl(wubacc, u & 63);
    bool val = (u < UU);
    vwr[r]  = val ? vw[u] : 0.f;
    wubr[r] = val ? wv : 0.f;
  }

  __syncthreads();   // drains vmcnt: tile 0 ready; zeros visible

  float* outb = out + (size_t)b * NSENT * DD;
  int cur = 0;

  #pragma unroll 1
  for (int t = 0; t < NSENT; ++t) {
    // ---- issue tile t+1 async loads into the other buffer ----
    if (t + 1 < NSENT) {
      const float* nb = base + (size_t)(t + 1) * (SEC * DD);
      float* lb = &fbuf[cur ^ 1][0];
      #pragma unroll
      for (int c = 0; c < 4; ++c) {
        int chunk = 4 * w + c;
        int g = chunk * 64 + lane;
        if (g < 1000) GL16(nb + g * 4, lb + chunk * 256);
      }
    }

    // ---- MFMA: read f32 frags from LDS, cvt to bf16, accumulate C[u][s] ----
    const float* fb = &fbuf[cur][0];
    f32x4 acc[3];
    #pragma unroll
    for (int st = 0; st < 3; ++st) { f32x4 z = {0.f,0.f,0.f,0.f}; acc[st] = z; }
    #pragma unroll
    for (int kt = 0; kt < 4; ++kt) {
      #pragma unroll
      for (int st = 0; st < 3; ++st) {
        int off = (st * 16 + col) * DD + kt * 32 + grp * 8;
        f32x4 fa = *(const f32x4*)(fb + off);
        f32x4 fbv = *(const f32x4*)(fb + off + 4);
        bf16x8 hf = cvt8(fa, fbv);
        acc[st] = __builtin_amdgcn_mfma_f32_16x16x32_bf16(afrag[kt], hf, acc[st], 0, 0, 0);
      }
    }

    // ---- partial e[s]: sum over this wave's u rows ----
    #pragma unroll
    for (int st = 0; st < 3; ++st) {
      float s = 0.f;
      #pragma unroll
      for (int r = 0; r < 4; ++r) {
        float x = acc[st][r] + wubr[r];
        float E = __expf(2.f * x);
        float tt = 1.f - 2.f * __builtin_amdgcn_rcpf(E + 1.f);
        s = fmaf(tt, vwr[r], s);
      }
      s += __shfl_xor(s, 16);
      s += __shfl_xor(s, 32);
      if (grp == 0) epart[st * 64 + col * 4 + w] = s;
    }
    __syncthreads();   // B2 (also drains t+1 loads; they had MFMA+epilogue to land)

    // ---- softmax over s<40, NO max pass (|e| <= sum|vw| ~ 2.2, exp-safe) ----
    f32x4 q0 = *(const f32x4*)&epart[col * 4];
    f32x4 q1 = *(const f32x4*)&epart[64 + col * 4];
    f32x4 q2 = *(const f32x4*)&epart[128 + col * 4];
    float e0 = (q0[0] + q0[1]) + (q0[2] + q0[3]);
    float e1 = (q1[0] + q1[1]) + (q1[2] + q1[3]);
    float e2 = (q2[0] + q2[1]) + (q2[2] + q2[3]);
    float p0 = __expf(e0);
    float p1 = __expf(e1);
    float p2 = (col < 8) ? __expf(e2) : 0.f;
    float sum = p0 + p1 + p2;
    sum += __shfl_xor(sum, 1);
    sum += __shfl_xor(sum, 2);
    sum += __shfl_xor(sum, 4);
    sum += __shfl_xor(sum, 8);
    float rinv = __builtin_amdgcn_rcpf(sum);
    if (w == 0 && grp == 0) {
      alphas[col]      = p0 * rinv;
      alphas[16 + col] = p1 * rinv;
      if (col < 8) alphas[32 + col] = p2 * rinv;
    }
    __syncthreads();   // B3

    // ---- out: wave w owns d in [25w, 25w+25); direct store, no combine ----
    if (lane < 25) {
      const float* colp = fb + 25 * w + lane;
      float a0 = 0.f, a1 = 0.f;
      #pragma unroll
      for (int s = 0; s < SEC; s += 2) {
        a0 = fmaf(alphas[s],     colp[s * DD], a0);
        a1 = fmaf(alphas[s + 1], colp[(s + 1) * DD], a1);
      }
      outb[t * DD + 25 * w + lane] = a0 + a1;
    }
    __syncthreads();   // Bend: all reads of fbuf[cur] done; next iter stages into it
    cur ^= 1;
  }
}

extern "C" void kernel_launch(void* const* d_in, const int* in_sizes, int n_in,
                              void* d_out, int out_size, void* d_ws, size_t ws_size,
                              hipStream_t stream) {
  const float* inputs = (const float*)d_in[0];
  const float* vw     = (const float*)d_in[1];
  const float* wh     = (const float*)d_in[2];
  const float* wu     = (const float*)d_in[3];
  const float* bw     = (const float*)d_in[4];
  float* out = (float*)d_out;

  doc_kernel<<<NB, 256, 0, stream>>>(inputs, vw, wh, wu, bw, out);
}